// Round 1
// baseline (3387.199 us; speedup 1.0000x reference)
//
#include <hip/hip_runtime.h>
#include <math.h>

#define BATCH 4
#define P 3072
#define NROW (BATCH * P)      // 12288
#define RCH 24                // row chunks for v partial pass (128 rows each)
#define MAXIT 50

__device__ inline float waveReduceSum(float v) {
#pragma unroll
  for (int off = 32; off > 0; off >>= 1) v += __shfl_xor(v, off, 64);
  return v;
}
__device__ inline float waveReduceMax(float v) {
#pragma unroll
  for (int off = 32; off > 0; off >>= 1) v = fmaxf(v, __shfl_xor(v, off, 64));
  return v;
}

// x2[b][i] = sum_k x[b][i][k]^2 ; y2 likewise. 8 rows per 256-thread block.
__global__ __launch_bounds__(256) void sq_kernel(const float* __restrict__ x,
                                                 const float* __restrict__ y,
                                                 float* __restrict__ x2,
                                                 float* __restrict__ y2) {
  int t = threadIdx.x;
  int row = blockIdx.x * 8 + (t >> 5);   // 0..24575
  int k = t & 31;
  const float* src = x;
  float* dst = x2;
  int r = row;
  if (row >= NROW) { src = y; dst = y2; r = row - NROW; }
  float vv = src[(size_t)r * 32 + k];
  float sq = vv * vv;
#pragma unroll
  for (int off = 16; off > 0; off >>= 1) sq += __shfl_xor(sq, off, 32);
  if (k == 0) dst[r] = sq;
}

// C[b][i][j] = x2_i + y2_j - 2 * dot(x_i, y_j). 64x64 tile per block.
__global__ __launch_bounds__(256) void c_kernel(const float* __restrict__ x,
                                                const float* __restrict__ y,
                                                const float* __restrict__ x2,
                                                const float* __restrict__ y2,
                                                float* __restrict__ C) {
  __shared__ float xs[64][33];   // +1 pad: LDS reads conflict-free / 2-way
  __shared__ float ys[64][33];
  int t = threadIdx.x;
  int b = blockIdx.z;
  int i0 = blockIdx.x * 64;
  int j0 = blockIdx.y * 64;
  const float4* xg = (const float4*)(x + ((size_t)b * P + i0) * 32);
  const float4* yg = (const float4*)(y + ((size_t)b * P + j0) * 32);
#pragma unroll
  for (int k = 0; k < 2; ++k) {
    int f4 = t + k * 256;              // 0..511 over 64x32 tile
    int row = f4 >> 3;
    int col = (f4 & 7) << 2;
    float4 xv = xg[f4];
    xs[row][col] = xv.x; xs[row][col + 1] = xv.y; xs[row][col + 2] = xv.z; xs[row][col + 3] = xv.w;
    float4 yv = yg[f4];
    ys[row][col] = yv.x; ys[row][col + 1] = yv.y; ys[row][col + 2] = yv.z; ys[row][col + 3] = yv.w;
  }
  __syncthreads();
  int ti = t >> 4, tj = t & 15;
  int ib = ti * 4, jb = tj * 4;
  float acc[4][4];
#pragma unroll
  for (int a = 0; a < 4; ++a)
#pragma unroll
    for (int bb = 0; bb < 4; ++bb) acc[a][bb] = 0.f;
#pragma unroll 8
  for (int k = 0; k < 32; ++k) {
    float xa[4], yb[4];
#pragma unroll
    for (int a = 0; a < 4; ++a) xa[a] = xs[ib + a][k];
#pragma unroll
    for (int bb = 0; bb < 4; ++bb) yb[bb] = ys[jb + bb][k];
#pragma unroll
    for (int a = 0; a < 4; ++a)
#pragma unroll
      for (int bb = 0; bb < 4; ++bb) acc[a][bb] = fmaf(xa[a], yb[bb], acc[a][bb]);
  }
  float y2r[4];
#pragma unroll
  for (int bb = 0; bb < 4; ++bb) y2r[bb] = y2[b * P + j0 + jb + bb];
#pragma unroll
  for (int a = 0; a < 4; ++a) {
    float x2r = x2[b * P + i0 + ib + a];
    float4 o;
    o.x = x2r + y2r[0] - 2.f * acc[a][0];
    o.y = x2r + y2r[1] - 2.f * acc[a][1];
    o.z = x2r + y2r[2] - 2.f * acc[a][2];
    o.w = x2r + y2r[3] - 2.f * acc[a][3];
    float* rowp = C + ((size_t)b * P + i0 + ib + a) * P + j0;
    ((float4*)rowp)[tj] = o;
  }
}

// u-update: one block per (b,i) row. u_new = eps*log_mu - eps*LSE_j((v_j - C_ij)/eps)
__global__ __launch_bounds__(256) void u_kernel(const float* __restrict__ C,
                                                const float* __restrict__ v,
                                                float* __restrict__ u,
                                                float* __restrict__ errbuf,
                                                const int* __restrict__ done_arr,
                                                int it, float log_mu) {
  if (done_arr[it]) return;
  int bi = blockIdx.x;                 // b*P + i
  int b = bi / P;
  const float4* Crow = (const float4*)(C + (size_t)bi * P);
  const float4* v4 = (const float4*)(v + (size_t)b * P);
  int t = threadIdx.x;
  float a[12];
  float m = -1e30f;
#pragma unroll
  for (int k = 0; k < 3; ++k) {
    float4 c = Crow[t + k * 256];
    float4 vv = v4[t + k * 256];
    a[4 * k + 0] = (vv.x - c.x) * 10.0f;
    a[4 * k + 1] = (vv.y - c.y) * 10.0f;
    a[4 * k + 2] = (vv.z - c.z) * 10.0f;
    a[4 * k + 3] = (vv.w - c.w) * 10.0f;
    m = fmaxf(m, fmaxf(fmaxf(a[4 * k], a[4 * k + 1]), fmaxf(a[4 * k + 2], a[4 * k + 3])));
  }
  m = waveReduceMax(m);
  __shared__ float redm[4];
  __shared__ float reds[4];
  int wid = t >> 6;
  if ((t & 63) == 0) redm[wid] = m;
  __syncthreads();
  float M = fmaxf(fmaxf(redm[0], redm[1]), fmaxf(redm[2], redm[3]));
  float s = 0.f;
#pragma unroll
  for (int k = 0; k < 12; ++k) s += __expf(a[k] - M);
  s = waveReduceSum(s);
  if ((t & 63) == 0) reds[wid] = s;
  __syncthreads();
  if (t == 0) {
    float S = reds[0] + reds[1] + reds[2] + reds[3];
    float L = M + __logf(S);
    float un = 0.1f * (log_mu - L);
    float uo = u[bi];
    u[bi] = un;
    errbuf[bi] = fabsf(un - uo);
  }
}

// v partial pass: block = (b, col-tile of 256, row-chunk of 128). Online LSE, 4-way ILP.
__global__ __launch_bounds__(256) void vpart_kernel(const float* __restrict__ C,
                                                    const float* __restrict__ u,
                                                    float* __restrict__ vpart,
                                                    const int* __restrict__ done_arr,
                                                    int it) {
  if (done_arr[it]) return;
  int blk = blockIdx.x;
  int b = blk / (12 * RCH);
  int rem = blk - b * (12 * RCH);
  int ct = rem / RCH;
  int rc = rem - ct * RCH;
  int col = ct * 256 + threadIdx.x;
  int i0 = rc * 128;
  const float* Cp = C + ((size_t)b * P + i0) * P + col;
  const float* ub = u + b * P + i0;
  float m0 = -1e30f, m1 = -1e30f, m2 = -1e30f, m3 = -1e30f;
  float s0 = 0.f, s1 = 0.f, s2 = 0.f, s3 = 0.f;
  for (int r = 0; r < 32; ++r) {
    float c0 = Cp[(size_t)r * P];
    float c1 = Cp[(size_t)(r + 32) * P];
    float c2 = Cp[(size_t)(r + 64) * P];
    float c3 = Cp[(size_t)(r + 96) * P];
    float a0 = (ub[r] - c0) * 10.f;
    float a1 = (ub[r + 32] - c1) * 10.f;
    float a2 = (ub[r + 64] - c2) * 10.f;
    float a3 = (ub[r + 96] - c3) * 10.f;
    float n0 = fmaxf(m0, a0); s0 = s0 * __expf(m0 - n0) + __expf(a0 - n0); m0 = n0;
    float n1 = fmaxf(m1, a1); s1 = s1 * __expf(m1 - n1) + __expf(a1 - n1); m1 = n1;
    float n2 = fmaxf(m2, a2); s2 = s2 * __expf(m2 - n2) + __expf(a2 - n2); m2 = n2;
    float n3 = fmaxf(m3, a3); s3 = s3 * __expf(m3 - n3) + __expf(a3 - n3); m3 = n3;
  }
  float M = fmaxf(fmaxf(m0, m1), fmaxf(m2, m3));
  float s = s0 * __expf(m0 - M) + s1 * __expf(m1 - M) +
            s2 * __expf(m2 - M) + s3 * __expf(m3 - M);
  vpart[((size_t)(b * RCH + rc)) * P + col] = M + __logf(s);
}

// combine partials -> v_new; block 0 also computes the convergence flag for it+1
__global__ __launch_bounds__(256) void vcomb_kernel(const float* __restrict__ vpart,
                                                    float* __restrict__ v,
                                                    const float* __restrict__ errbuf,
                                                    int* __restrict__ done_arr,
                                                    int it, float log_nu) {
  int dn = done_arr[it];
  int t = threadIdx.x;
  int gid = blockIdx.x * 256 + t;      // 0..12287 == b*P + col
  if (!dn) {
    int b = gid / P;
    int col = gid - b * P;
    float vals[RCH];
    float m = -1e30f;
#pragma unroll
    for (int r = 0; r < RCH; ++r) {
      vals[r] = vpart[((size_t)(b * RCH + r)) * P + col];
      m = fmaxf(m, vals[r]);
    }
    float s = 0.f;
#pragma unroll
    for (int r = 0; r < RCH; ++r) s += __expf(vals[r] - m);
    float L = m + __logf(s);
    v[gid] = 0.1f * (log_nu - L);
  }
  if (blockIdx.x == 0) {
    __shared__ float red[4];
    float loc = 0.f;
    if (!dn) {
      for (int idx = t; idx < NROW; idx += 256) loc += errbuf[idx];
    }
    loc = waveReduceSum(loc);
    if ((t & 63) == 0) red[t >> 6] = loc;
    __syncthreads();
    if (t == 0) {
      float tot = red[0] + red[1] + red[2] + red[3];
      done_arr[it + 1] = (dn || (tot * 0.25f < 0.1f)) ? 1 : 0;
    }
  }
}

// pi = exp((-C + u_i + v_j)/eps); per-row partial of sum(pi*C) into partial[bi]
__global__ __launch_bounds__(256) void pi_kernel(const float* __restrict__ C,
                                                 const float* __restrict__ u,
                                                 const float* __restrict__ v,
                                                 float* __restrict__ pi,
                                                 float* __restrict__ partial) {
  int bi = blockIdx.x;
  int b = bi / P;
  float ui = u[bi];
  const float4* Crow = (const float4*)(C + (size_t)bi * P);
  const float4* v4 = (const float4*)(v + (size_t)b * P);
  float4* pirow = (float4*)(pi + (size_t)bi * P);
  int t = threadIdx.x;
  float acc = 0.f;
#pragma unroll
  for (int k = 0; k < 3; ++k) {
    float4 c = Crow[t + k * 256];
    float4 vv = v4[t + k * 256];
    float4 p;
    p.x = __expf((ui + vv.x - c.x) * 10.f);
    p.y = __expf((ui + vv.y - c.y) * 10.f);
    p.z = __expf((ui + vv.z - c.z) * 10.f);
    p.w = __expf((ui + vv.w - c.w) * 10.f);
    pirow[t + k * 256] = p;
    acc += p.x * c.x + p.y * c.y + p.z * c.z + p.w * c.w;
  }
  acc = waveReduceSum(acc);
  __shared__ float red[4];
  if ((t & 63) == 0) red[t >> 6] = acc;
  __syncthreads();
  if (t == 0) partial[bi] = red[0] + red[1] + red[2] + red[3];
}

__global__ __launch_bounds__(256) void cost_kernel(const float* __restrict__ partial,
                                                   float* __restrict__ cost) {
  __shared__ float red[4];
  int t = threadIdx.x;
  for (int b = 0; b < BATCH; ++b) {
    float loc = 0.f;
    for (int idx = t; idx < P; idx += 256) loc += partial[b * P + idx];
    loc = waveReduceSum(loc);
    if ((t & 63) == 0) red[t >> 6] = loc;
    __syncthreads();
    if (t == 0) cost[b] = red[0] + red[1] + red[2] + red[3];
    __syncthreads();
  }
}

extern "C" void kernel_launch(void* const* d_in, const int* in_sizes, int n_in,
                              void* d_out, int out_size, void* d_ws, size_t ws_size,
                              hipStream_t stream) {
  (void)in_sizes; (void)n_in; (void)out_size; (void)ws_size;
  const float* x = (const float*)d_in[0];
  const float* y = (const float*)d_in[1];
  float* out = (float*)d_out;
  float* cost = out;                          // [4]
  float* pi = out + 4;                        // [4*3072*3072]
  float* C = pi + (size_t)BATCH * P * P;      // [4*3072*3072]

  float* u = (float*)d_ws;                    // 12288
  float* v = u + NROW;                        // 12288
  int* done_arr = (int*)(v + NROW);           // 64 ints (uses 51)
  float* errbuf = (float*)(done_arr + 64);    // 12288
  float* x2 = errbuf + NROW;                  // 12288
  float* y2 = x2 + NROW;                      // 12288
  float* vpart = y2 + NROW;                   // 4*24*3072 = 294912

  // zero u, v, done_arr (harness poisons ws each call)
  hipMemsetAsync(d_ws, 0, (size_t)(2 * NROW) * sizeof(float) + 64 * sizeof(int), stream);

  float log_mu = logf(1.0f / 3072.0f + 1e-8f);   // log_nu identical (P1==P2)

  sq_kernel<<<3072, 256, 0, stream>>>(x, y, x2, y2);
  c_kernel<<<dim3(48, 48, 4), 256, 0, stream>>>(x, y, x2, y2, C);

  for (int it = 0; it < MAXIT; ++it) {
    u_kernel<<<NROW, 256, 0, stream>>>(C, v, u, errbuf, done_arr, it, log_mu);
    vpart_kernel<<<BATCH * 12 * RCH, 256, 0, stream>>>(C, u, vpart, done_arr, it);
    vcomb_kernel<<<48, 256, 0, stream>>>(vpart, v, errbuf, done_arr, it, log_mu);
  }

  pi_kernel<<<NROW, 256, 0, stream>>>(C, u, v, pi, errbuf);
  cost_kernel<<<1, 256, 0, stream>>>(errbuf, cost);
}